// Round 3
// baseline (427.374 us; speedup 1.0000x reference)
//
#include <hip/hip_runtime.h>
#include <math.h>

// Problem constants (from reference)
constexpr int cS  = 16;   // sequence
constexpr int cB  = 8;    // batch
constexpr int cNC = 5;    // classes
constexpr int cD  = 256;  // hidden
constexpr int cH  = 16;   // heads
constexpr int cP  = 16;   // patches
constexpr int cPD = 49;   // patch dim
constexpr int cDFT = 128; // channel-mixer hidden
constexpr int cEP  = 64;  // token-mixer hidden (EF*P)
#define LEPS 1e-5f

__device__ __forceinline__ float gelu_t(float x) {
  float x3 = x * x * x;
  return 0.5f * x * (1.0f + tanhf(0.7978845608028654f * (x + 0.044715f * x3)));
}
__device__ __forceinline__ float sigm(float x) { return 1.0f / (1.0f + __expf(-x)); }

// ---------------- embed: patchify + one-hot concat + linear ----------------
__global__ __launch_bounds__(256) void k_embed(const float* __restrict__ x,
                                               const int* __restrict__ fb,
                                               const float* __restrict__ inW,
                                               const float* __restrict__ inb,
                                               float* __restrict__ h) {
  const int blk = blockIdx.x;
  const int p  = blk & 15;
  const int sb = blk >> 4;
  const int ph = p >> 2, pw = p & 3;
  __shared__ float sx[cPD];
  const int t = threadIdx.x;
  if (t < cPD) {
    const int p1 = t / 7, p2 = t % 7;
    sx[t] = x[(size_t)sb * 784 + (ph * 7 + p1) * 28 + (pw * 7 + p2)];
  }
  __syncthreads();
  const int cls = fb[sb];
  float acc = inb[t] + inW[(size_t)(cPD + cls) * cD + t];
#pragma unroll
  for (int j = 0; j < cPD; ++j) acc += sx[j] * inW[(size_t)j * cD + t];
  h[((size_t)sb * cP + p) * cD + t] = acc;
}

// ---------------- token SRWM: wave-centric, 4 instances/wave ---------------
// R2: zero barriers, zero LDS. All cross-row comm = intra-16-lane shuffles.
// x for all 16 steps prefetched into registers (inputs don't depend on scan).
// grid = 128 blocks x 256 threads; instance = (b, d); feature axis = patch r.
__global__ __launch_bounds__(256) void k_tok_srwm(
    float* __restrict__ h, const float* __restrict__ Wy0, const float* __restrict__ Wq0,
    const float* __restrict__ Wk0, const float* __restrict__ wb0,
    const float* __restrict__ lng, const float* __restrict__ lnb) {
  const int t    = threadIdx.x;
  const int lane = t & 63;
  const int w    = t >> 6;
  const int r    = lane & 15;
  const int li   = lane >> 4;                 // 0..3 instance within wave
  const int b    = blockIdx.x >> 4;
  const int d    = ((blockIdx.x & 15) << 4) + (w << 2) + li;
  float wy[16], wq[16], wk[16], wbr[16];
#pragma unroll
  for (int j = 0; j < 16; ++j) {
    wy[j]  = Wy0[r * 16 + j];
    wq[j]  = Wq0[r * 16 + j];
    wk[j]  = Wk0[r * 16 + j];
    wbr[j] = wb0[(r & 3) * 16 + j];
  }
  const float gg = lng[r], bb = lnb[r];
  float xp[16];
#pragma unroll
  for (int s = 0; s < 16; ++s)
    xp[s] = h[((size_t)(s * cB + b) * cP + r) * cD + d];
  for (int s = 0; s < cS; ++s) {
    const float xv = xp[s];
    float y = 0.f, q = 0.f, k = 0.f, bt = 0.f;
#pragma unroll
    for (int j = 0; j < 16; ++j) {
      const float xj = __shfl(xv, j, 16);
      y += wy[j] * xj; q += wq[j] * xj; k += wk[j] * xj; bt += wbr[j] * xj;
    }
    const float bsig = sigm(bt);
    const float b0  = __shfl(bsig, 0, 16);
    const float b1v = __shfl(bsig, 1, 16);
    const float b2v = __shfl(bsig, 2, 16);
    const float b3v = __shfl(bsig, 3, 16);
    float mq = q, mk = k;
#pragma unroll
    for (int o = 1; o < 16; o <<= 1) {
      mq = fmaxf(mq, __shfl_xor(mq, o, 16));
      mk = fmaxf(mk, __shfl_xor(mk, o, 16));
    }
    const float eq = __expf(q - mq), ek = __expf(k - mk);
    float sq = eq, sk = ek;
#pragma unroll
    for (int o = 1; o < 16; o <<= 1) {
      sq += __shfl_xor(sq, o, 16);
      sk += __shfl_xor(sk, o, 16);
    }
    const float qs = eq / sq, ks = ek / sk;
    float ay = 0.f, vyk = 0.f, vqq = 0.f, vqk = 0.f, vkq = 0.f, vkk = 0.f, vbq = 0.f, vbk = 0.f;
    float ksj[16];
#pragma unroll
    for (int j = 0; j < 16; ++j) {
      const float qj = __shfl(qs, j, 16);
      const float kj = __shfl(ks, j, 16);
      ksj[j] = kj;
      ay  += wy[j]  * qj; vyk += wy[j]  * kj;
      vqq += wq[j]  * qj; vqk += wq[j]  * kj;
      vkq += wk[j]  * qj; vkk += wk[j]  * kj;
      vbq += wbr[j] * qj; vbk += wbr[j] * kj;
    }
    float ma = ay;
#pragma unroll
    for (int o = 1; o < 16; o <<= 1) ma = fmaxf(ma, __shfl_xor(ma, o, 16));
    const float ea = __expf(ay - ma);
    float sa = ea;
#pragma unroll
    for (int o = 1; o < 16; o <<= 1) sa += __shfl_xor(sa, o, 16);
    const float vyq = ea / sa;
    const float cy = b0 * (vyq - vyk), cq = b1v * (vqq - vqk);
    const float ck = b2v * (vkq - vkk), cb = b3v * (vbq - vbk);
#pragma unroll
    for (int j = 0; j < 16; ++j) {
      wy[j] += cy * ksj[j]; wq[j] += cq * ksj[j]; wk[j] += ck * ksj[j]; wbr[j] += cb * ksj[j];
    }
    float s1 = y, s2 = y * y;
#pragma unroll
    for (int o = 1; o < 16; o <<= 1) {
      s1 += __shfl_xor(s1, o, 16);
      s2 += __shfl_xor(s2, o, 16);
    }
    const float m = s1 * 0.0625f;
    const float var = s2 * 0.0625f - m * m;
    h[((size_t)(s * cB + b) * cP + r) * cD + d] = (y - m) * rsqrtf(var + LEPS) * gg + bb;
  }
}

// ---------------- token mixer: LN(D) then FFN over patch axis --------------
__global__ __launch_bounds__(256) void k_tok_mixer(
    float* __restrict__ h, const float* __restrict__ g, const float* __restrict__ bta,
    const float* __restrict__ W1, const float* __restrict__ b1,
    const float* __restrict__ W2, const float* __restrict__ b2) {
  const int sb = blockIdx.x;
  const int t = threadIdx.x;
  __shared__ float tile[16][256];
  __shared__ float W1s[16 * 64], W2s[64 * 16];
  __shared__ float mean_[16], rstd_[16];
  __shared__ float red[16][17], red2[16][17];
  const size_t base = (size_t)sb * cP * cD;
#pragma unroll
  for (int p = 0; p < 16; ++p) tile[p][t] = h[base + p * 256 + t];
  W1s[t] = W1[t]; W1s[t + 256] = W1[t + 256]; W1s[t + 512] = W1[t + 512]; W1s[t + 768] = W1[t + 768];
  W2s[t] = W2[t]; W2s[t + 256] = W2[t + 256]; W2s[t + 512] = W2[t + 512]; W2s[t + 768] = W2[t + 768];
  __syncthreads();
  const int p = t >> 4, l = t & 15;
  float ps = 0.f, ps2 = 0.f;
#pragma unroll
  for (int k = 0; k < 16; ++k) { const float v = tile[p][l + 16 * k]; ps += v; ps2 += v * v; }
  red[p][l] = ps; red2[p][l] = ps2;
  __syncthreads();
  if (t < 16) {
    float sm = 0.f, s2 = 0.f;
#pragma unroll
    for (int k = 0; k < 16; ++k) { sm += red[t][k]; s2 += red2[t][k]; }
    const float m = sm * (1.f / 256.f);
    mean_[t] = m;
    rstd_[t] = rsqrtf(s2 * (1.f / 256.f) - m * m + LEPS);
  }
  __syncthreads();
  const float gd = g[t], bd = bta[t];
  float v[16], out[16];
#pragma unroll
  for (int pp = 0; pp < 16; ++pp) {
    v[pp] = (tile[pp][t] - mean_[pp]) * rstd_[pp] * gd + bd;
    out[pp] = b2[pp];
  }
  for (int e = 0; e < cEP; ++e) {
    float acc = b1[e];
#pragma unroll
    for (int pp = 0; pp < 16; ++pp) acc += v[pp] * W1s[pp * 64 + e];
    const float ge = gelu_t(acc);
#pragma unroll
    for (int pp = 0; pp < 16; ++pp) out[pp] += ge * W2s[e * 16 + pp];
  }
#pragma unroll
  for (int pp = 0; pp < 16; ++pp) h[base + pp * 256 + t] = tile[pp][t] + out[pp];
}

// ---------------- channel SRWM: wave-centric, 4 heads/wave -----------------
// R2: intra-head comm = shuffles; only the 256-wide LN crosses waves ->
// exactly 1 barrier/step (double-buffered LDS partials). x prefetched.
// grid = B*P = 128 blocks x 256 threads.
__global__ __launch_bounds__(256) void k_ch_srwm(
    float* __restrict__ h, const float* __restrict__ Wy0, const float* __restrict__ Wq0,
    const float* __restrict__ Wk0, const float* __restrict__ wb0,
    const float* __restrict__ lng, const float* __restrict__ lnb) {
  const int t = threadIdx.x;
  const int w = t >> 6;
  const int hh = t >> 4, r = t & 15;
  const int bp = blockIdx.x;
  float wy[16], wq[16], wk[16], wbr[16];
#pragma unroll
  for (int j = 0; j < 16; ++j) {
    wy[j]  = Wy0[(hh * 16 + r) * 16 + j];
    wq[j]  = Wq0[(hh * 16 + r) * 16 + j];
    wk[j]  = Wk0[(hh * 16 + r) * 16 + j];
    wbr[j] = wb0[(hh * 4 + (r & 3)) * 16 + j];
  }
  const float gg = lng[t], bb = lnb[t];
  float xp[16];
#pragma unroll
  for (int s = 0; s < 16; ++s)
    xp[s] = h[(size_t)(s * cB * cP + bp) * cD + t];
  __shared__ float pS[2][4], pQ[2][4];
  for (int s = 0; s < cS; ++s) {
    const float xv = xp[s];
    float y = 0.f, q = 0.f, k = 0.f, bt = 0.f;
#pragma unroll
    for (int j = 0; j < 16; ++j) {
      const float xj = __shfl(xv, j, 16);
      y += wy[j] * xj; q += wq[j] * xj; k += wk[j] * xj; bt += wbr[j] * xj;
    }
    const float bsig = sigm(bt);
    const float b0  = __shfl(bsig, 0, 16);
    const float b1v = __shfl(bsig, 1, 16);
    const float b2v = __shfl(bsig, 2, 16);
    const float b3v = __shfl(bsig, 3, 16);
    float mq = q, mk = k;
#pragma unroll
    for (int o = 1; o < 16; o <<= 1) {
      mq = fmaxf(mq, __shfl_xor(mq, o, 16));
      mk = fmaxf(mk, __shfl_xor(mk, o, 16));
    }
    const float eq = __expf(q - mq), ek = __expf(k - mk);
    float sq = eq, sk = ek;
#pragma unroll
    for (int o = 1; o < 16; o <<= 1) {
      sq += __shfl_xor(sq, o, 16);
      sk += __shfl_xor(sk, o, 16);
    }
    const float qs = eq / sq, ks = ek / sk;
    float ay = 0.f, vyk = 0.f, vqq = 0.f, vqk = 0.f, vkq = 0.f, vkk = 0.f, vbq = 0.f, vbk = 0.f;
    float ksj[16];
#pragma unroll
    for (int j = 0; j < 16; ++j) {
      const float qj = __shfl(qs, j, 16);
      const float kj = __shfl(ks, j, 16);
      ksj[j] = kj;
      ay  += wy[j]  * qj; vyk += wy[j]  * kj;
      vqq += wq[j]  * qj; vqk += wq[j]  * kj;
      vkq += wk[j]  * qj; vkk += wk[j]  * kj;
      vbq += wbr[j] * qj; vbk += wbr[j] * kj;
    }
    float ma = ay;
#pragma unroll
    for (int o = 1; o < 16; o <<= 1) ma = fmaxf(ma, __shfl_xor(ma, o, 16));
    const float ea = __expf(ay - ma);
    float sa = ea;
#pragma unroll
    for (int o = 1; o < 16; o <<= 1) sa += __shfl_xor(sa, o, 16);
    const float vyq = ea / sa;
    const float cy = b0 * (vyq - vyk), cq = b1v * (vqq - vqk);
    const float ck = b2v * (vkq - vkk), cb = b3v * (vbq - vbk);
#pragma unroll
    for (int j = 0; j < 16; ++j) {
      wy[j] += cy * ksj[j]; wq[j] += cq * ksj[j]; wk[j] += ck * ksj[j]; wbr[j] += cb * ksj[j];
    }
    // LN over 256: wave butterfly + 1 barrier (double-buffered partials)
    float s1 = y, s2 = y * y;
#pragma unroll
    for (int o = 1; o < 64; o <<= 1) {
      s1 += __shfl_xor(s1, o, 64);
      s2 += __shfl_xor(s2, o, 64);
    }
    const int db = s & 1;
    if ((t & 63) == 0) { pS[db][w] = s1; pQ[db][w] = s2; }
    __syncthreads();
    const float sm  = pS[db][0] + pS[db][1] + pS[db][2] + pS[db][3];
    const float sq2 = pQ[db][0] + pQ[db][1] + pQ[db][2] + pQ[db][3];
    const float m = sm * (1.f / 256.f);
    const float var = sq2 * (1.f / 256.f) - m * m;
    h[(size_t)(s * cB * cP + bp) * cD + t] = (y - m) * rsqrtf(var + LEPS) * gg + bb;
  }
}

// ---------------- channel mixer: LN(D) + 256->128->256 FFN ----------------
// R2: first GEMV split across 2 threads/hidden-unit (halves serial chain).
__global__ __launch_bounds__(256) void k_ch_mixer(
    float* __restrict__ h, const float* __restrict__ g, const float* __restrict__ bta,
    const float* __restrict__ W1, const float* __restrict__ b1,
    const float* __restrict__ W2, const float* __restrict__ b2) {
  const int row = blockIdx.x;
  const int t = threadIdx.x;
  __shared__ float lnv[256], hid[128], part[256];
  __shared__ float sum4[4], sq4[4];
  const size_t base = (size_t)row * cD;
  const float v = h[base + t];
  float rs = v, rq = v * v;
#pragma unroll
  for (int o = 32; o > 0; o >>= 1) { rs += __shfl_down(rs, o, 64); rq += __shfl_down(rq, o, 64); }
  if ((t & 63) == 0) { sum4[t >> 6] = rs; sq4[t >> 6] = rq; }
  __syncthreads();
  const float m = (sum4[0] + sum4[1] + sum4[2] + sum4[3]) * (1.f / 256.f);
  const float var = (sq4[0] + sq4[1] + sq4[2] + sq4[3]) * (1.f / 256.f) - m * m;
  lnv[t] = (v - m) * rsqrtf(var + LEPS) * g[t] + bta[t];
  __syncthreads();
  {
    const int e = t & 127, hf = t >> 7;
    float acc = hf ? 0.f : b1[e];
    const int j0 = hf * 128;
    for (int j = j0; j < j0 + 128; ++j) acc += lnv[j] * W1[(size_t)j * cDFT + e];
    part[t] = acc;
  }
  __syncthreads();
  if (t < cDFT) hid[t] = gelu_t(part[t] + part[t + 128]);
  __syncthreads();
  float acc2 = b2[t];
  for (int e = 0; e < cDFT; ++e) acc2 += hid[e] * W2[(size_t)e * cD + t];
  h[base + t] = v + acc2;
}

// ---------------- final LN + mean over patches -----------------------------
// R2: wave handles 4 patches with float4 loads; LN via wave butterfly;
// single barrier for the 4-wave mean combine.
__global__ __launch_bounds__(256) void k_fln_mean(
    const float* __restrict__ h, const float* __restrict__ gg, const float* __restrict__ bbv,
    float* __restrict__ o) {
  const int sb = blockIdx.x;
  const int t = threadIdx.x;
  const int lane = t & 63, w = t >> 6;
  const float4 g4 = ((const float4*)gg)[lane];
  const float4 b4 = ((const float4*)bbv)[lane];
  float a0 = 0.f, a1 = 0.f, a2 = 0.f, a3 = 0.f;
  for (int pp = 0; pp < 4; ++pp) {
    const int p = w * 4 + pp;
    const float4 v4 = ((const float4*)(h + ((size_t)sb * cP + p) * cD))[lane];
    float s1 = v4.x + v4.y + v4.z + v4.w;
    float s2 = v4.x * v4.x + v4.y * v4.y + v4.z * v4.z + v4.w * v4.w;
#pragma unroll
    for (int o2 = 1; o2 < 64; o2 <<= 1) {
      s1 += __shfl_xor(s1, o2, 64);
      s2 += __shfl_xor(s2, o2, 64);
    }
    const float m = s1 * (1.f / 256.f);
    const float rst = rsqrtf(s2 * (1.f / 256.f) - m * m + LEPS);
    a0 += (v4.x - m) * rst * g4.x + b4.x;
    a1 += (v4.y - m) * rst * g4.y + b4.y;
    a2 += (v4.z - m) * rst * g4.z + b4.z;
    a3 += (v4.w - m) * rst * g4.w + b4.w;
  }
  __shared__ float sacc[4][256];
  float4* sp = (float4*)sacc[w];
  sp[lane] = make_float4(a0, a1, a2, a3);
  __syncthreads();
  o[(size_t)sb * cD + t] = (sacc[0][t] + sacc[1][t] + sacc[2][t] + sacc[3][t]) * (1.f / 16.f);
}

// ---------------- output SRWM (batch=B) + final projection ----------------
// R2: wave-centric like channel; 2 barriers/step (LN combine, proj combine).
// grid = B = 8 blocks.
__global__ __launch_bounds__(256) void k_out_srwm(
    const float* __restrict__ gin, float* __restrict__ outp,
    const float* __restrict__ Wy0, const float* __restrict__ Wq0,
    const float* __restrict__ Wk0, const float* __restrict__ wb0,
    const float* __restrict__ lng, const float* __restrict__ lnb,
    const float* __restrict__ outW, const float* __restrict__ outb) {
  const int t = threadIdx.x;
  const int w = t >> 6;
  const int hh = t >> 4, r = t & 15;
  const int b = blockIdx.x;
  float wy[16], wq[16], wk[16], wbr[16];
#pragma unroll
  for (int j = 0; j < 16; ++j) {
    wy[j]  = Wy0[(hh * 16 + r) * 16 + j];
    wq[j]  = Wq0[(hh * 16 + r) * 16 + j];
    wk[j]  = Wk0[(hh * 16 + r) * 16 + j];
    wbr[j] = wb0[(hh * 4 + (r & 3)) * 16 + j];
  }
  float wrow[cNC];
#pragma unroll
  for (int c = 0; c < cNC; ++c) wrow[c] = outW[(size_t)t * cNC + c];
  const float gg = lng[t], bb = lnb[t];
  float xp[16];
#pragma unroll
  for (int s = 0; s < 16; ++s)
    xp[s] = gin[(size_t)(s * cB + b) * cD + t];
  __shared__ float pS[2][4], pQ[2][4];
  __shared__ float pr[2][4][cNC];
  for (int s = 0; s < cS; ++s) {
    const float xv = xp[s];
    float y = 0.f, q = 0.f, k = 0.f, bt = 0.f;
#pragma unroll
    for (int j = 0; j < 16; ++j) {
      const float xj = __shfl(xv, j, 16);
      y += wy[j] * xj; q += wq[j] * xj; k += wk[j] * xj; bt += wbr[j] * xj;
    }
    const float bsig = sigm(bt);
    const float b0  = __shfl(bsig, 0, 16);
    const float b1v = __shfl(bsig, 1, 16);
    const float b2v = __shfl(bsig, 2, 16);
    const float b3v = __shfl(bsig, 3, 16);
    float mq = q, mk = k;
#pragma unroll
    for (int o = 1; o < 16; o <<= 1) {
      mq = fmaxf(mq, __shfl_xor(mq, o, 16));
      mk = fmaxf(mk, __shfl_xor(mk, o, 16));
    }
    const float eq = __expf(q - mq), ek = __expf(k - mk);
    float sq = eq, sk = ek;
#pragma unroll
    for (int o = 1; o < 16; o <<= 1) {
      sq += __shfl_xor(sq, o, 16);
      sk += __shfl_xor(sk, o, 16);
    }
    const float qs = eq / sq, ks = ek / sk;
    float ay = 0.f, vyk = 0.f, vqq = 0.f, vqk = 0.f, vkq = 0.f, vkk = 0.f, vbq = 0.f, vbk = 0.f;
    float ksj[16];
#pragma unroll
    for (int j = 0; j < 16; ++j) {
      const float qj = __shfl(qs, j, 16);
      const float kj = __shfl(ks, j, 16);
      ksj[j] = kj;
      ay  += wy[j]  * qj; vyk += wy[j]  * kj;
      vqq += wq[j]  * qj; vqk += wq[j]  * kj;
      vkq += wk[j]  * qj; vkk += wk[j]  * kj;
      vbq += wbr[j] * qj; vbk += wbr[j] * kj;
    }
    float ma = ay;
#pragma unroll
    for (int o = 1; o < 16; o <<= 1) ma = fmaxf(ma, __shfl_xor(ma, o, 16));
    const float ea = __expf(ay - ma);
    float sa = ea;
#pragma unroll
    for (int o = 1; o < 16; o <<= 1) sa += __shfl_xor(sa, o, 16);
    const float vyq = ea / sa;
    const float cy = b0 * (vyq - vyk), cq = b1v * (vqq - vqk);
    const float ck = b2v * (vkq - vkk), cb = b3v * (vbq - vbk);
#pragma unroll
    for (int j = 0; j < 16; ++j) {
      wy[j] += cy * ksj[j]; wq[j] += cq * ksj[j]; wk[j] += ck * ksj[j]; wbr[j] += cb * ksj[j];
    }
    float s1 = y, s2 = y * y;
#pragma unroll
    for (int o = 1; o < 64; o <<= 1) {
      s1 += __shfl_xor(s1, o, 64);
      s2 += __shfl_xor(s2, o, 64);
    }
    const int db = s & 1;
    if ((t & 63) == 0) { pS[db][w] = s1; pQ[db][w] = s2; }
    __syncthreads();
    const float sm  = pS[db][0] + pS[db][1] + pS[db][2] + pS[db][3];
    const float sq2 = pQ[db][0] + pQ[db][1] + pQ[db][2] + pQ[db][3];
    const float m = sm * (1.f / 256.f);
    const float var = sq2 * (1.f / 256.f) - m * m;
    const float lnt = (y - m) * rsqrtf(var + LEPS) * gg + bb;
    float pv[cNC];
#pragma unroll
    for (int c = 0; c < cNC; ++c) {
      float p = lnt * wrow[c];
#pragma unroll
      for (int o = 1; o < 64; o <<= 1) p += __shfl_xor(p, o, 64);
      pv[c] = p;
    }
    if ((t & 63) == 0) {
#pragma unroll
      for (int c = 0; c < cNC; ++c) pr[db][w][c] = pv[c];
    }
    __syncthreads();
    if (t < cNC) {
      outp[(size_t)(s * cB + b) * cNC + t] =
          outb[t] + pr[db][0][t] + pr[db][1][t] + pr[db][2][t] + pr[db][3][t];
    }
  }
}

extern "C" void kernel_launch(void* const* d_in, const int* in_sizes, int n_in,
                              void* d_out, int out_size, void* d_ws, size_t ws_size,
                              hipStream_t stream) {
  const float* x     = (const float*)d_in[0];
  const int*   fb    = (const int*)d_in[1];
  const float* inW   = (const float*)d_in[2];
  const float* inb   = (const float*)d_in[3];
  const float* tkWy  = (const float*)d_in[4];
  const float* tkWq  = (const float*)d_in[5];
  const float* tkWk  = (const float*)d_in[6];
  const float* tkwb  = (const float*)d_in[7];
  const float* tklng = (const float*)d_in[8];
  const float* tklnb = (const float*)d_in[9];
  const float* tkmg  = (const float*)d_in[10];
  const float* tkmb  = (const float*)d_in[11];
  const float* tkmW1 = (const float*)d_in[12];
  const float* tkmb1 = (const float*)d_in[13];
  const float* tkmW2 = (const float*)d_in[14];
  const float* tkmb2 = (const float*)d_in[15];
  const float* chWy  = (const float*)d_in[16];
  const float* chWq  = (const float*)d_in[17];
  const float* chWk  = (const float*)d_in[18];
  const float* chwb  = (const float*)d_in[19];
  const float* chlng = (const float*)d_in[20];
  const float* chlnb = (const float*)d_in[21];
  const float* chmg  = (const float*)d_in[22];
  const float* chmb  = (const float*)d_in[23];
  const float* chmW1 = (const float*)d_in[24];
  const float* chmb1 = (const float*)d_in[25];
  const float* chmW2 = (const float*)d_in[26];
  const float* chmb2 = (const float*)d_in[27];
  const float* flng  = (const float*)d_in[28];
  const float* flnb  = (const float*)d_in[29];
  const float* oWy   = (const float*)d_in[30];
  const float* oWq   = (const float*)d_in[31];
  const float* oWk   = (const float*)d_in[32];
  const float* owb   = (const float*)d_in[33];
  const float* olng  = (const float*)d_in[34];
  const float* olnb  = (const float*)d_in[35];
  const float* outW  = (const float*)d_in[36];
  const float* outb  = (const float*)d_in[37];

  float* h    = (float*)d_ws;                               // (S,B,P,D) fp32 = 2 MB
  float* gbuf = h + (size_t)cS * cB * cP * cD;              // (S,B,D)
  float* outp = (float*)d_out;                              // (S,B,NC) fp32

  k_embed<<<dim3(cS * cB * cP), dim3(256), 0, stream>>>(x, fb, inW, inb, h);
  for (int i = 0; i < 2; ++i) {
    k_tok_srwm<<<dim3(128), dim3(256), 0, stream>>>(
        h, tkWy + i * 256, tkWq + i * 256, tkWk + i * 256, tkwb + i * 64,
        tklng + i * 16, tklnb + i * 16);
    k_tok_mixer<<<dim3(cS * cB), dim3(256), 0, stream>>>(
        h, tkmg + i * 256, tkmb + i * 256, tkmW1 + i * 1024, tkmb1 + i * 64,
        tkmW2 + i * 1024, tkmb2 + i * 16);
    k_ch_srwm<<<dim3(cB * cP), dim3(256), 0, stream>>>(
        h, chWy + i * 4096, chWq + i * 4096, chWk + i * 4096, chwb + i * 1024,
        chlng + i * 256, chlnb + i * 256);
    k_ch_mixer<<<dim3(cS * cB * cP), dim3(256), 0, stream>>>(
        h, chmg + i * 256, chmb + i * 256, chmW1 + i * 32768, chmb1 + i * 128,
        chmW2 + i * 32768, chmb2 + i * 256);
  }
  k_fln_mean<<<dim3(cS * cB), dim3(256), 0, stream>>>(h, flng, flnb, gbuf);
  k_out_srwm<<<dim3(cB), dim3(256), 0, stream>>>(
      gbuf, outp, oWy, oWq, oWk, owb, olng, olnb, outW, outb);
}

// Round 4
// 387.956 us; speedup vs baseline: 1.1016x; 1.1016x over previous
//
#include <hip/hip_runtime.h>
#include <math.h>

// Problem constants (from reference)
constexpr int cS  = 16;   // sequence
constexpr int cB  = 8;    // batch
constexpr int cNC = 5;    // classes
constexpr int cD  = 256;  // hidden
constexpr int cH  = 16;   // heads
constexpr int cP  = 16;   // patches
constexpr int cPD = 49;   // patch dim
constexpr int cDFT = 128; // channel-mixer hidden
constexpr int cEP  = 64;  // token-mixer hidden (EF*P)
#define LEPS 1e-5f

__device__ __forceinline__ float gelu_t(float x) {
  float x3 = x * x * x;
  return 0.5f * x * (1.0f + tanhf(0.7978845608028654f * (x + 0.044715f * x3)));
}
__device__ __forceinline__ float sigm(float x) { return 1.0f / (1.0f + __expf(-x)); }

// ---------------- embed: patchify + one-hot concat + linear ----------------
__global__ __launch_bounds__(256) void k_embed(const float* __restrict__ x,
                                               const int* __restrict__ fb,
                                               const float* __restrict__ inW,
                                               const float* __restrict__ inb,
                                               float* __restrict__ h) {
  const int blk = blockIdx.x;
  const int p  = blk & 15;
  const int sb = blk >> 4;
  const int ph = p >> 2, pw = p & 3;
  __shared__ float sx[cPD];
  const int t = threadIdx.x;
  if (t < cPD) {
    const int p1 = t / 7, p2 = t % 7;
    sx[t] = x[(size_t)sb * 784 + (ph * 7 + p1) * 28 + (pw * 7 + p2)];
  }
  __syncthreads();
  const int cls = fb[sb];
  float acc = inb[t] + inW[(size_t)(cPD + cls) * cD + t];
#pragma unroll
  for (int j = 0; j < cPD; ++j) acc += sx[j] * inW[(size_t)j * cD + t];
  h[((size_t)sb * cP + p) * cD + t] = acc;
}

// ---------------- token SRWM: wave-centric, 4 instances/wave ---------------
// R2: zero barriers, zero LDS. All cross-row comm = intra-16-lane shuffles.
__global__ __launch_bounds__(256) void k_tok_srwm(
    float* __restrict__ h, const float* __restrict__ Wy0, const float* __restrict__ Wq0,
    const float* __restrict__ Wk0, const float* __restrict__ wb0,
    const float* __restrict__ lng, const float* __restrict__ lnb) {
  const int t    = threadIdx.x;
  const int lane = t & 63;
  const int w    = t >> 6;
  const int r    = lane & 15;
  const int li   = lane >> 4;                 // 0..3 instance within wave
  const int b    = blockIdx.x >> 4;
  const int d    = ((blockIdx.x & 15) << 4) + (w << 2) + li;
  float wy[16], wq[16], wk[16], wbr[16];
#pragma unroll
  for (int j = 0; j < 16; ++j) {
    wy[j]  = Wy0[r * 16 + j];
    wq[j]  = Wq0[r * 16 + j];
    wk[j]  = Wk0[r * 16 + j];
    wbr[j] = wb0[(r & 3) * 16 + j];
  }
  const float gg = lng[r], bb = lnb[r];
  float xp[16];
#pragma unroll
  for (int s = 0; s < 16; ++s)
    xp[s] = h[((size_t)(s * cB + b) * cP + r) * cD + d];
  for (int s = 0; s < cS; ++s) {
    const float xv = xp[s];
    float y = 0.f, q = 0.f, k = 0.f, bt = 0.f;
#pragma unroll
    for (int j = 0; j < 16; ++j) {
      const float xj = __shfl(xv, j, 16);
      y += wy[j] * xj; q += wq[j] * xj; k += wk[j] * xj; bt += wbr[j] * xj;
    }
    const float bsig = sigm(bt);
    const float b0  = __shfl(bsig, 0, 16);
    const float b1v = __shfl(bsig, 1, 16);
    const float b2v = __shfl(bsig, 2, 16);
    const float b3v = __shfl(bsig, 3, 16);
    float mq = q, mk = k;
#pragma unroll
    for (int o = 1; o < 16; o <<= 1) {
      mq = fmaxf(mq, __shfl_xor(mq, o, 16));
      mk = fmaxf(mk, __shfl_xor(mk, o, 16));
    }
    const float eq = __expf(q - mq), ek = __expf(k - mk);
    float sq = eq, sk = ek;
#pragma unroll
    for (int o = 1; o < 16; o <<= 1) {
      sq += __shfl_xor(sq, o, 16);
      sk += __shfl_xor(sk, o, 16);
    }
    const float qs = eq / sq, ks = ek / sk;
    float ay = 0.f, vyk = 0.f, vqq = 0.f, vqk = 0.f, vkq = 0.f, vkk = 0.f, vbq = 0.f, vbk = 0.f;
    float ksj[16];
#pragma unroll
    for (int j = 0; j < 16; ++j) {
      const float qj = __shfl(qs, j, 16);
      const float kj = __shfl(ks, j, 16);
      ksj[j] = kj;
      ay  += wy[j]  * qj; vyk += wy[j]  * kj;
      vqq += wq[j]  * qj; vqk += wq[j]  * kj;
      vkq += wk[j]  * qj; vkk += wk[j]  * kj;
      vbq += wbr[j] * qj; vbk += wbr[j] * kj;
    }
    float ma = ay;
#pragma unroll
    for (int o = 1; o < 16; o <<= 1) ma = fmaxf(ma, __shfl_xor(ma, o, 16));
    const float ea = __expf(ay - ma);
    float sa = ea;
#pragma unroll
    for (int o = 1; o < 16; o <<= 1) sa += __shfl_xor(sa, o, 16);
    const float vyq = ea / sa;
    const float cy = b0 * (vyq - vyk), cq = b1v * (vqq - vqk);
    const float ck = b2v * (vkq - vkk), cb = b3v * (vbq - vbk);
#pragma unroll
    for (int j = 0; j < 16; ++j) {
      wy[j] += cy * ksj[j]; wq[j] += cq * ksj[j]; wk[j] += ck * ksj[j]; wbr[j] += cb * ksj[j];
    }
    float s1 = y, s2 = y * y;
#pragma unroll
    for (int o = 1; o < 16; o <<= 1) {
      s1 += __shfl_xor(s1, o, 16);
      s2 += __shfl_xor(s2, o, 16);
    }
    const float m = s1 * 0.0625f;
    const float var = s2 * 0.0625f - m * m;
    h[((size_t)(s * cB + b) * cP + r) * cD + d] = (y - m) * rsqrtf(var + LEPS) * gg + bb;
  }
}

// ---------------- token mixer: LN(D) then FFN over patch axis --------------
__global__ __launch_bounds__(256) void k_tok_mixer(
    float* __restrict__ h, const float* __restrict__ g, const float* __restrict__ bta,
    const float* __restrict__ W1, const float* __restrict__ b1,
    const float* __restrict__ W2, const float* __restrict__ b2) {
  const int sb = blockIdx.x;
  const int t = threadIdx.x;
  __shared__ float tile[16][256];
  __shared__ float W1s[16 * 64], W2s[64 * 16];
  __shared__ float mean_[16], rstd_[16];
  __shared__ float red[16][17], red2[16][17];
  const size_t base = (size_t)sb * cP * cD;
#pragma unroll
  for (int p = 0; p < 16; ++p) tile[p][t] = h[base + p * 256 + t];
  W1s[t] = W1[t]; W1s[t + 256] = W1[t + 256]; W1s[t + 512] = W1[t + 512]; W1s[t + 768] = W1[t + 768];
  W2s[t] = W2[t]; W2s[t + 256] = W2[t + 256]; W2s[t + 512] = W2[t + 512]; W2s[t + 768] = W2[t + 768];
  __syncthreads();
  const int p = t >> 4, l = t & 15;
  float ps = 0.f, ps2 = 0.f;
#pragma unroll
  for (int k = 0; k < 16; ++k) { const float v = tile[p][l + 16 * k]; ps += v; ps2 += v * v; }
  red[p][l] = ps; red2[p][l] = ps2;
  __syncthreads();
  if (t < 16) {
    float sm = 0.f, s2 = 0.f;
#pragma unroll
    for (int k = 0; k < 16; ++k) { sm += red[t][k]; s2 += red2[t][k]; }
    const float m = sm * (1.f / 256.f);
    mean_[t] = m;
    rstd_[t] = rsqrtf(s2 * (1.f / 256.f) - m * m + LEPS);
  }
  __syncthreads();
  const float gd = g[t], bd = bta[t];
  float v[16], out[16];
#pragma unroll
  for (int pp = 0; pp < 16; ++pp) {
    v[pp] = (tile[pp][t] - mean_[pp]) * rstd_[pp] * gd + bd;
    out[pp] = b2[pp];
  }
  for (int e = 0; e < cEP; ++e) {
    float acc = b1[e];
#pragma unroll
    for (int pp = 0; pp < 16; ++pp) acc += v[pp] * W1s[pp * 64 + e];
    const float ge = gelu_t(acc);
#pragma unroll
    for (int pp = 0; pp < 16; ++pp) out[pp] += ge * W2s[e * 16 + pp];
  }
#pragma unroll
  for (int pp = 0; pp < 16; ++pp) h[base + pp * 256 + t] = tile[pp][t] + out[pp];
}

// ---------------- channel SRWM: wave-centric, 4 heads/wave -----------------
__global__ __launch_bounds__(256) void k_ch_srwm(
    float* __restrict__ h, const float* __restrict__ Wy0, const float* __restrict__ Wq0,
    const float* __restrict__ Wk0, const float* __restrict__ wb0,
    const float* __restrict__ lng, const float* __restrict__ lnb) {
  const int t = threadIdx.x;
  const int w = t >> 6;
  const int hh = t >> 4, r = t & 15;
  const int bp = blockIdx.x;
  float wy[16], wq[16], wk[16], wbr[16];
#pragma unroll
  for (int j = 0; j < 16; ++j) {
    wy[j]  = Wy0[(hh * 16 + r) * 16 + j];
    wq[j]  = Wq0[(hh * 16 + r) * 16 + j];
    wk[j]  = Wk0[(hh * 16 + r) * 16 + j];
    wbr[j] = wb0[(hh * 4 + (r & 3)) * 16 + j];
  }
  const float gg = lng[t], bb = lnb[t];
  float xp[16];
#pragma unroll
  for (int s = 0; s < 16; ++s)
    xp[s] = h[(size_t)(s * cB * cP + bp) * cD + t];
  __shared__ float pS[2][4], pQ[2][4];
  for (int s = 0; s < cS; ++s) {
    const float xv = xp[s];
    float y = 0.f, q = 0.f, k = 0.f, bt = 0.f;
#pragma unroll
    for (int j = 0; j < 16; ++j) {
      const float xj = __shfl(xv, j, 16);
      y += wy[j] * xj; q += wq[j] * xj; k += wk[j] * xj; bt += wbr[j] * xj;
    }
    const float bsig = sigm(bt);
    const float b0  = __shfl(bsig, 0, 16);
    const float b1v = __shfl(bsig, 1, 16);
    const float b2v = __shfl(bsig, 2, 16);
    const float b3v = __shfl(bsig, 3, 16);
    float mq = q, mk = k;
#pragma unroll
    for (int o = 1; o < 16; o <<= 1) {
      mq = fmaxf(mq, __shfl_xor(mq, o, 16));
      mk = fmaxf(mk, __shfl_xor(mk, o, 16));
    }
    const float eq = __expf(q - mq), ek = __expf(k - mk);
    float sq = eq, sk = ek;
#pragma unroll
    for (int o = 1; o < 16; o <<= 1) {
      sq += __shfl_xor(sq, o, 16);
      sk += __shfl_xor(sk, o, 16);
    }
    const float qs = eq / sq, ks = ek / sk;
    float ay = 0.f, vyk = 0.f, vqq = 0.f, vqk = 0.f, vkq = 0.f, vkk = 0.f, vbq = 0.f, vbk = 0.f;
    float ksj[16];
#pragma unroll
    for (int j = 0; j < 16; ++j) {
      const float qj = __shfl(qs, j, 16);
      const float kj = __shfl(ks, j, 16);
      ksj[j] = kj;
      ay  += wy[j]  * qj; vyk += wy[j]  * kj;
      vqq += wq[j]  * qj; vqk += wq[j]  * kj;
      vkq += wk[j]  * qj; vkk += wk[j]  * kj;
      vbq += wbr[j] * qj; vbk += wbr[j] * kj;
    }
    float ma = ay;
#pragma unroll
    for (int o = 1; o < 16; o <<= 1) ma = fmaxf(ma, __shfl_xor(ma, o, 16));
    const float ea = __expf(ay - ma);
    float sa = ea;
#pragma unroll
    for (int o = 1; o < 16; o <<= 1) sa += __shfl_xor(sa, o, 16);
    const float vyq = ea / sa;
    const float cy = b0 * (vyq - vyk), cq = b1v * (vqq - vqk);
    const float ck = b2v * (vkq - vkk), cb = b3v * (vbq - vbk);
#pragma unroll
    for (int j = 0; j < 16; ++j) {
      wy[j] += cy * ksj[j]; wq[j] += cq * ksj[j]; wk[j] += ck * ksj[j]; wbr[j] += cb * ksj[j];
    }
    float s1 = y, s2 = y * y;
#pragma unroll
    for (int o = 1; o < 64; o <<= 1) {
      s1 += __shfl_xor(s1, o, 64);
      s2 += __shfl_xor(s2, o, 64);
    }
    const int db = s & 1;
    if ((t & 63) == 0) { pS[db][w] = s1; pQ[db][w] = s2; }
    __syncthreads();
    const float sm  = pS[db][0] + pS[db][1] + pS[db][2] + pS[db][3];
    const float sq2 = pQ[db][0] + pQ[db][1] + pQ[db][2] + pQ[db][3];
    const float m = sm * (1.f / 256.f);
    const float var = sq2 * (1.f / 256.f) - m * m;
    h[(size_t)(s * cB * cP + bp) * cD + t] = (y - m) * rsqrtf(var + LEPS) * gg + bb;
  }
}

// ---------------- channel mixer v2: 8 rows/block GEMM-style ----------------
// R3: was 2048 blocks x GEMV (1 MAC per W load from L2, 512 MB L2 traffic,
// 55 us). Now 256 blocks x 8 rows: W loaded as float4, reused across 8 rows
// held in LDS; 2048 MACs/thread. Thread map: r = t>>5 (2 rows/wave),
// GEMV1 lane owns 4 e's, GEMV2 lane owns 8 d's.
__global__ __launch_bounds__(256) void k_ch_mixer(
    float* __restrict__ h, const float* __restrict__ g, const float* __restrict__ bta,
    const float* __restrict__ W1, const float* __restrict__ b1,
    const float* __restrict__ W2, const float* __restrict__ b2) {
  const int t = threadIdx.x;
  const int row0 = blockIdx.x * 8;
  __shared__ float xv[8][256];
  __shared__ float lnv[8][256];
  __shared__ float hid[8][128];
  // cooperative load: 8 consecutive rows = 2048 consecutive floats
  const float4* hp4 = (const float4*)(h + (size_t)row0 * cD);
  ((float4*)xv)[t]       = hp4[t];
  ((float4*)xv)[t + 256] = hp4[t + 256];
  __syncthreads();
  // LN: half-wave (32 lanes) per row; lane owns 8 dims
  const int r = t >> 5, l = t & 31;
  {
    const float4 a = ((const float4*)xv[r])[l * 2];
    const float4 c = ((const float4*)xv[r])[l * 2 + 1];
    float s1 = a.x + a.y + a.z + a.w + c.x + c.y + c.z + c.w;
    float s2 = a.x * a.x + a.y * a.y + a.z * a.z + a.w * a.w +
               c.x * c.x + c.y * c.y + c.z * c.z + c.w * c.w;
#pragma unroll
    for (int o = 1; o < 32; o <<= 1) {
      s1 += __shfl_xor(s1, o, 32);
      s2 += __shfl_xor(s2, o, 32);
    }
    const float m = s1 * (1.f / 256.f);
    const float rst = rsqrtf(s2 * (1.f / 256.f) - m * m + LEPS);
    const float4 g0 = ((const float4*)g)[l * 2];
    const float4 g1 = ((const float4*)g)[l * 2 + 1];
    const float4 t0 = ((const float4*)bta)[l * 2];
    const float4 t1 = ((const float4*)bta)[l * 2 + 1];
    float4 o0, o1;
    o0.x = (a.x - m) * rst * g0.x + t0.x; o0.y = (a.y - m) * rst * g0.y + t0.y;
    o0.z = (a.z - m) * rst * g0.z + t0.z; o0.w = (a.w - m) * rst * g0.w + t0.w;
    o1.x = (c.x - m) * rst * g1.x + t1.x; o1.y = (c.y - m) * rst * g1.y + t1.y;
    o1.z = (c.z - m) * rst * g1.z + t1.z; o1.w = (c.w - m) * rst * g1.w + t1.w;
    ((float4*)lnv[r])[l * 2]     = o0;
    ((float4*)lnv[r])[l * 2 + 1] = o1;
  }
  __syncthreads();
  // GEMV1 (256->128) x 8 rows: thread (r, e4=l*4); W1 float4 reused per row-pair
  {
    const float4* W1f = (const float4*)W1;   // [256][32] float4
    float4 acc = ((const float4*)b1)[l];
    for (int j = 0; j < 256; ++j) {
      const float4 wv = W1f[j * 32 + l];
      const float xj = lnv[r][j];
      acc.x += xj * wv.x; acc.y += xj * wv.y; acc.z += xj * wv.z; acc.w += xj * wv.w;
    }
    float4 hv;
    hv.x = gelu_t(acc.x); hv.y = gelu_t(acc.y); hv.z = gelu_t(acc.z); hv.w = gelu_t(acc.w);
    ((float4*)hid[r])[l] = hv;
  }
  __syncthreads();
  // GEMV2 (128->256) x 8 rows: thread (r, d8=l*8)
  {
    const float4* W2f = (const float4*)W2;   // [128][64] float4
    float4 a0 = ((const float4*)b2)[l * 2];
    float4 a1 = ((const float4*)b2)[l * 2 + 1];
    for (int ee = 0; ee < 128; ++ee) {
      const float4 w0 = W2f[ee * 64 + l * 2];
      const float4 w1 = W2f[ee * 64 + l * 2 + 1];
      const float xh = hid[r][ee];
      a0.x += xh * w0.x; a0.y += xh * w0.y; a0.z += xh * w0.z; a0.w += xh * w0.w;
      a1.x += xh * w1.x; a1.y += xh * w1.y; a1.z += xh * w1.z; a1.w += xh * w1.w;
    }
    const float4 x0 = ((const float4*)xv[r])[l * 2];
    const float4 x1 = ((const float4*)xv[r])[l * 2 + 1];
    a0.x += x0.x; a0.y += x0.y; a0.z += x0.z; a0.w += x0.w;
    a1.x += x1.x; a1.y += x1.y; a1.z += x1.z; a1.w += x1.w;
    float4* op = (float4*)(h + ((size_t)row0 + r) * cD);
    op[l * 2]     = a0;
    op[l * 2 + 1] = a1;
  }
}

// ---------------- final LN + mean over patches -----------------------------
__global__ __launch_bounds__(256) void k_fln_mean(
    const float* __restrict__ h, const float* __restrict__ gg, const float* __restrict__ bbv,
    float* __restrict__ o) {
  const int sb = blockIdx.x;
  const int t = threadIdx.x;
  const int lane = t & 63, w = t >> 6;
  const float4 g4 = ((const float4*)gg)[lane];
  const float4 b4 = ((const float4*)bbv)[lane];
  float a0 = 0.f, a1 = 0.f, a2 = 0.f, a3 = 0.f;
  for (int pp = 0; pp < 4; ++pp) {
    const int p = w * 4 + pp;
    const float4 v4 = ((const float4*)(h + ((size_t)sb * cP + p) * cD))[lane];
    float s1 = v4.x + v4.y + v4.z + v4.w;
    float s2 = v4.x * v4.x + v4.y * v4.y + v4.z * v4.z + v4.w * v4.w;
#pragma unroll
    for (int o2 = 1; o2 < 64; o2 <<= 1) {
      s1 += __shfl_xor(s1, o2, 64);
      s2 += __shfl_xor(s2, o2, 64);
    }
    const float m = s1 * (1.f / 256.f);
    const float rst = rsqrtf(s2 * (1.f / 256.f) - m * m + LEPS);
    a0 += (v4.x - m) * rst * g4.x + b4.x;
    a1 += (v4.y - m) * rst * g4.y + b4.y;
    a2 += (v4.z - m) * rst * g4.z + b4.z;
    a3 += (v4.w - m) * rst * g4.w + b4.w;
  }
  __shared__ float sacc[4][256];
  float4* sp = (float4*)sacc[w];
  sp[lane] = make_float4(a0, a1, a2, a3);
  __syncthreads();
  o[(size_t)sb * cD + t] = (sacc[0][t] + sacc[1][t] + sacc[2][t] + sacc[3][t]) * (1.f / 16.f);
}

// ---------------- output SRWM (batch=B) + final projection ----------------
__global__ __launch_bounds__(256) void k_out_srwm(
    const float* __restrict__ gin, float* __restrict__ outp,
    const float* __restrict__ Wy0, const float* __restrict__ Wq0,
    const float* __restrict__ Wk0, const float* __restrict__ wb0,
    const float* __restrict__ lng, const float* __restrict__ lnb,
    const float* __restrict__ outW, const float* __restrict__ outb) {
  const int t = threadIdx.x;
  const int w = t >> 6;
  const int hh = t >> 4, r = t & 15;
  const int b = blockIdx.x;
  float wy[16], wq[16], wk[16], wbr[16];
#pragma unroll
  for (int j = 0; j < 16; ++j) {
    wy[j]  = Wy0[(hh * 16 + r) * 16 + j];
    wq[j]  = Wq0[(hh * 16 + r) * 16 + j];
    wk[j]  = Wk0[(hh * 16 + r) * 16 + j];
    wbr[j] = wb0[(hh * 4 + (r & 3)) * 16 + j];
  }
  float wrow[cNC];
#pragma unroll
  for (int c = 0; c < cNC; ++c) wrow[c] = outW[(size_t)t * cNC + c];
  const float gg = lng[t], bb = lnb[t];
  float xp[16];
#pragma unroll
  for (int s = 0; s < 16; ++s)
    xp[s] = gin[(size_t)(s * cB + b) * cD + t];
  __shared__ float pS[2][4], pQ[2][4];
  __shared__ float pr[2][4][cNC];
  for (int s = 0; s < cS; ++s) {
    const float xv = xp[s];
    float y = 0.f, q = 0.f, k = 0.f, bt = 0.f;
#pragma unroll
    for (int j = 0; j < 16; ++j) {
      const float xj = __shfl(xv, j, 16);
      y += wy[j] * xj; q += wq[j] * xj; k += wk[j] * xj; bt += wbr[j] * xj;
    }
    const float bsig = sigm(bt);
    const float b0  = __shfl(bsig, 0, 16);
    const float b1v = __shfl(bsig, 1, 16);
    const float b2v = __shfl(bsig, 2, 16);
    const float b3v = __shfl(bsig, 3, 16);
    float mq = q, mk = k;
#pragma unroll
    for (int o = 1; o < 16; o <<= 1) {
      mq = fmaxf(mq, __shfl_xor(mq, o, 16));
      mk = fmaxf(mk, __shfl_xor(mk, o, 16));
    }
    const float eq = __expf(q - mq), ek = __expf(k - mk);
    float sq = eq, sk = ek;
#pragma unroll
    for (int o = 1; o < 16; o <<= 1) {
      sq += __shfl_xor(sq, o, 16);
      sk += __shfl_xor(sk, o, 16);
    }
    const float qs = eq / sq, ks = ek / sk;
    float ay = 0.f, vyk = 0.f, vqq = 0.f, vqk = 0.f, vkq = 0.f, vkk = 0.f, vbq = 0.f, vbk = 0.f;
    float ksj[16];
#pragma unroll
    for (int j = 0; j < 16; ++j) {
      const float qj = __shfl(qs, j, 16);
      const float kj = __shfl(ks, j, 16);
      ksj[j] = kj;
      ay  += wy[j]  * qj; vyk += wy[j]  * kj;
      vqq += wq[j]  * qj; vqk += wq[j]  * kj;
      vkq += wk[j]  * qj; vkk += wk[j]  * kj;
      vbq += wbr[j] * qj; vbk += wbr[j] * kj;
    }
    float ma = ay;
#pragma unroll
    for (int o = 1; o < 16; o <<= 1) ma = fmaxf(ma, __shfl_xor(ma, o, 16));
    const float ea = __expf(ay - ma);
    float sa = ea;
#pragma unroll
    for (int o = 1; o < 16; o <<= 1) sa += __shfl_xor(sa, o, 16);
    const float vyq = ea / sa;
    const float cy = b0 * (vyq - vyk), cq = b1v * (vqq - vqk);
    const float ck = b2v * (vkq - vkk), cb = b3v * (vbq - vbk);
#pragma unroll
    for (int j = 0; j < 16; ++j) {
      wy[j] += cy * ksj[j]; wq[j] += cq * ksj[j]; wk[j] += ck * ksj[j]; wbr[j] += cb * ksj[j];
    }
    float s1 = y, s2 = y * y;
#pragma unroll
    for (int o = 1; o < 64; o <<= 1) {
      s1 += __shfl_xor(s1, o, 64);
      s2 += __shfl_xor(s2, o, 64);
    }
    const int db = s & 1;
    if ((t & 63) == 0) { pS[db][w] = s1; pQ[db][w] = s2; }
    __syncthreads();
    const float sm  = pS[db][0] + pS[db][1] + pS[db][2] + pS[db][3];
    const float sq2 = pQ[db][0] + pQ[db][1] + pQ[db][2] + pQ[db][3];
    const float m = sm * (1.f / 256.f);
    const float var = sq2 * (1.f / 256.f) - m * m;
    const float lnt = (y - m) * rsqrtf(var + LEPS) * gg + bb;
    float pv[cNC];
#pragma unroll
    for (int c = 0; c < cNC; ++c) {
      float p = lnt * wrow[c];
#pragma unroll
      for (int o = 1; o < 64; o <<= 1) p += __shfl_xor(p, o, 64);
      pv[c] = p;
    }
    if ((t & 63) == 0) {
#pragma unroll
      for (int c = 0; c < cNC; ++c) pr[db][w][c] = pv[c];
    }
    __syncthreads();
    if (t < cNC) {
      outp[(size_t)(s * cB + b) * cNC + t] =
          outb[t] + pr[db][0][t] + pr[db][1][t] + pr[db][2][t] + pr[db][3][t];
    }
  }
}

extern "C" void kernel_launch(void* const* d_in, const int* in_sizes, int n_in,
                              void* d_out, int out_size, void* d_ws, size_t ws_size,
                              hipStream_t stream) {
  const float* x     = (const float*)d_in[0];
  const int*   fb    = (const int*)d_in[1];
  const float* inW   = (const float*)d_in[2];
  const float* inb   = (const float*)d_in[3];
  const float* tkWy  = (const float*)d_in[4];
  const float* tkWq  = (const float*)d_in[5];
  const float* tkWk  = (const float*)d_in[6];
  const float* tkwb  = (const float*)d_in[7];
  const float* tklng = (const float*)d_in[8];
  const float* tklnb = (const float*)d_in[9];
  const float* tkmg  = (const float*)d_in[10];
  const float* tkmb  = (const float*)d_in[11];
  const float* tkmW1 = (const float*)d_in[12];
  const float* tkmb1 = (const float*)d_in[13];
  const float* tkmW2 = (const float*)d_in[14];
  const float* tkmb2 = (const float*)d_in[15];
  const float* chWy  = (const float*)d_in[16];
  const float* chWq  = (const float*)d_in[17];
  const float* chWk  = (const float*)d_in[18];
  const float* chwb  = (const float*)d_in[19];
  const float* chlng = (const float*)d_in[20];
  const float* chlnb = (const float*)d_in[21];
  const float* chmg  = (const float*)d_in[22];
  const float* chmb  = (const float*)d_in[23];
  const float* chmW1 = (const float*)d_in[24];
  const float* chmb1 = (const float*)d_in[25];
  const float* chmW2 = (const float*)d_in[26];
  const float* chmb2 = (const float*)d_in[27];
  const float* flng  = (const float*)d_in[28];
  const float* flnb  = (const float*)d_in[29];
  const float* oWy   = (const float*)d_in[30];
  const float* oWq   = (const float*)d_in[31];
  const float* oWk   = (const float*)d_in[32];
  const float* owb   = (const float*)d_in[33];
  const float* olng  = (const float*)d_in[34];
  const float* olnb  = (const float*)d_in[35];
  const float* outW  = (const float*)d_in[36];
  const float* outb  = (const float*)d_in[37];

  float* h    = (float*)d_ws;                               // (S,B,P,D) fp32 = 2 MB
  float* gbuf = h + (size_t)cS * cB * cP * cD;              // (S,B,D)
  float* outp = (float*)d_out;                              // (S,B,NC) fp32

  k_embed<<<dim3(cS * cB * cP), dim3(256), 0, stream>>>(x, fb, inW, inb, h);
  for (int i = 0; i < 2; ++i) {
    k_tok_srwm<<<dim3(128), dim3(256), 0, stream>>>(
        h, tkWy + i * 256, tkWq + i * 256, tkWk + i * 256, tkwb + i * 64,
        tklng + i * 16, tklnb + i * 16);
    k_tok_mixer<<<dim3(cS * cB), dim3(256), 0, stream>>>(
        h, tkmg + i * 256, tkmb + i * 256, tkmW1 + i * 1024, tkmb1 + i * 64,
        tkmW2 + i * 1024, tkmb2 + i * 16);
    k_ch_srwm<<<dim3(cB * cP), dim3(256), 0, stream>>>(
        h, chWy + i * 4096, chWq + i * 4096, chWk + i * 4096, chwb + i * 1024,
        chlng + i * 256, chlnb + i * 256);
    k_ch_mixer<<<dim3(cS * cB * cP / 8), dim3(256), 0, stream>>>(
        h, chmg + i * 256, chmb + i * 256, chmW1 + i * 32768, chmb1 + i * 128,
        chmW2 + i * 32768, chmb2 + i * 256);
  }
  k_fln_mean<<<dim3(cS * cB), dim3(256), 0, stream>>>(h, flng, flnb, gbuf);
  k_out_srwm<<<dim3(cB), dim3(256), 0, stream>>>(
      gbuf, outp, oWy, oWq, oWk, owb, olng, olnb, outW, outb);
}